// Round 7
// baseline (780.468 us; speedup 1.0000x reference)
//
#include <hip/hip_runtime.h>
#include <math.h>

// R19: PERSISTENT SINGLE KERNEL. Budget solve across R1/R5/R6 shows ~10 us per
// dispatch boundary (~70-90 us of R1's 143.9). One dispatch, grid 512 = 2/CU
// (guaranteed resident: 40KB LDS, launch_bounds(256,2)), 5 in-kernel global
// barriers (atomic counter + __threadfence for cross-XCD L2 wb/inv) replace 7
// boundaries. Stage bodies are the R1-proven GEMM and R6-verified bupd/tT/rsv
// math, with tT spread over all 512 blocks (576 r16xb32 units - no serial tail).

// Problem constants
#define R_   1152
#define C_   10
#define D_   16
#define I_   8
#define B_   256
#define N_   160      // C_*D_
#define K_   9216     // R_*I_
#define KS_  32       // K-split across blocks
#define KC_  288      // K_/KS_ per block (9 chunks of 32 k = 4 r-rows)
#define NB_  512      // persistent grid (2 blocks/CU x 256 CU)

// workspace layout (float offsets); ~18.5 MB
#define OFF_TT    0                      // 2,949,120  tT[c][b][r]
#define OFF_BIJ   2949120                //   184,320  bij[r][n]
#define OFF_E     (OFF_BIJ + 184320)     //   184,320  E[r][n] = exp(bij)
#define OFF_NSA   (OFF_E + 184320)       //       160  nsumA
#define OFF_NSB   (OFF_NSA + 160)        //       160  nsumB
#define OFF_PART  (OFF_NSB + 160)        // 1,310,720  partials[ks][b][n]
#define OFF_BAR   (OFF_PART + 1310720)   //        64  barrier counter (memset 0)

__device__ __forceinline__ float f4c(const float4 v, int i) {
    return i == 0 ? v.x : i == 1 ? v.y : i == 2 ? v.z : v.w;
}

// ---------------------------------------------------------------------------
// Device-scope grid barrier: monotonic counter, goal = NB_ * round.
// __threadfence() (agent scope) emits the gfx950 L2 writeback/invalidate so
// plain stores made before the barrier are visible across XCDs after it.
__device__ __forceinline__ void gridbar(int* bar, int goal) {
    __syncthreads();
    if (threadIdx.x == 0) {
        __threadfence();   // release: drain stores, wb L2
        __hip_atomic_fetch_add(bar, 1, __ATOMIC_ACQ_REL, __HIP_MEMORY_SCOPE_AGENT);
        while (__hip_atomic_load(bar, __ATOMIC_ACQUIRE, __HIP_MEMORY_SCOPE_AGENT) < goal)
            __builtin_amdgcn_s_sleep(8);
        __threadfence();   // acquire: inv caches
    }
    __syncthreads();
}

// ---------------------------------------------------------------------------
// GEMM body (R1-proven): partials[ks][b*160+n] = sum_k u[b][k]*W[r][n][i]*cw,
// cw = E[r][n] (HASE) else 1. bt in [0,16), ks in [0,32). 40KB smem.
template <int HASE>
__device__ __forceinline__ void gemm_body(
    const float* __restrict__ u, const float* __restrict__ W,
    const float* __restrict__ E, float* __restrict__ partials,
    float* smem, int bt, int ks, int tid) {
    int wave = tid >> 6, lane = tid & 63;
    int ng = lane & 15, bg = lane >> 4;
    int b0 = bt * 16;
    int n0 = ng * 10;

    float acc[4][10];
#pragma unroll
    for (int m = 0; m < 4; ++m)
#pragma unroll
        for (int j = 0; j < 10; ++j) acc[m][j] = 0.0f;

    const float* ubase = u + (size_t)(b0 + bg * 4) * K_ + ks * KC_ + wave * 8;

    float4 wr[5];
    float  ee[5];
    float4 uc[8];
    {
        int r = ks * 36 + wave;
#pragma unroll
        for (int it = 0; it < 5; ++it) {
            int idx = it * 64 + lane;
            wr[it] = *(const float4*)(W + (size_t)r * 1280 + idx * 4);
            if (HASE) ee[it] = E[r * N_ + (idx >> 1)];
        }
#pragma unroll
        for (int m = 0; m < 4; ++m)
#pragma unroll
            for (int g = 0; g < 2; ++g)
                uc[m * 2 + g] = *(const float4*)(ubase + (size_t)m * K_ + g * 4);
    }

    int ldsbase = wave * 1280;
    for (int c = 0; c < 9; ++c) {
#pragma unroll
        for (int it = 0; it < 5; ++it) {
            int idx = it * 64 + lane;
            int n = idx >> 1, ih = (idx & 1) * 4;
            float e = HASE ? ee[it] : 1.0f;
            float* q = &smem[ldsbase + ih * 160 + n];
            q[0]   = wr[it].x * e;
            q[160] = wr[it].y * e;
            q[320] = wr[it].z * e;
            q[480] = wr[it].w * e;
        }
        float4 un[8];
        if (c < 8) {
            int r = ks * 36 + (c + 1) * 4 + wave;
#pragma unroll
            for (int it = 0; it < 5; ++it) {
                int idx = it * 64 + lane;
                wr[it] = *(const float4*)(W + (size_t)r * 1280 + idx * 4);
                if (HASE) ee[it] = E[r * N_ + (idx >> 1)];
            }
#pragma unroll
            for (int m = 0; m < 4; ++m)
#pragma unroll
                for (int g = 0; g < 2; ++g)
                    un[m * 2 + g] = *(const float4*)(ubase + (size_t)m * K_ + (c + 1) * 32 + g * 4);
        }
#pragma unroll
        for (int g = 0; g < 2; ++g) {
#pragma unroll
            for (int t4 = 0; t4 < 4; ++t4) {
                const float* wrow = &smem[ldsbase + (g * 4 + t4) * 160 + n0];
                float w[10];
#pragma unroll
                for (int j = 0; j < 10; j += 2) {
                    float2 ww = *(const float2*)(wrow + j);
                    w[j] = ww.x; w[j + 1] = ww.y;
                }
#pragma unroll
                for (int m = 0; m < 4; ++m) {
                    float uav = f4c(uc[m * 2 + g], t4);
#pragma unroll
                    for (int j = 0; j < 10; ++j)
                        acc[m][j] = fmaf(uav, w[j], acc[m][j]);
                }
            }
        }
        if (c < 8) {
#pragma unroll
            for (int q2 = 0; q2 < 8; ++q2) uc[q2] = un[q2];
        }
    }

    __syncthreads();
#pragma unroll
    for (int m = 0; m < 4; ++m)
#pragma unroll
        for (int j = 0; j < 10; ++j)
            smem[wave * 2560 + (bg * 4 + m) * N_ + n0 + j] = acc[m][j];
    __syncthreads();
    float* outp = partials + (size_t)ks * (B_ * N_) + (size_t)b0 * N_;
    for (int f = tid; f < 2560; f += 256)
        outp[f] = smem[f] + smem[2560 + f] + smem[5120 + f] + smem[7680 + f];
}

// ---------------------------------------------------------------------------
// tT unit (r-tile 16 x b-tile 32), 576 units over 512 blocks (64 do two):
//   wsl[rr][c*8+i] = sum_d W[r0+rr][c][d][i]  (redundant x8 b-tiles, L2-hot)
//   tT[c][b][r0+r] = sum_i wsl[r][c*8+i] * u[b][r0+r][i]   (64B write segs)
__device__ __forceinline__ void tT_unit(const float* __restrict__ u,
                                        const float* __restrict__ W,
                                        float* __restrict__ tT,
                                        int unit, int tid, float* wsl) {
    int r0 = (unit >> 3) * 16;
    int b0 = (unit & 7) * 32;
    __syncthreads();                        // smem handoff
    for (int q = tid; q < 1280; q += 256) {
        int rr = q / 80, rem = q % 80;      // rem = c*8+i
        const float* p = W + (size_t)(r0 + rr) * 1280 + (rem >> 3) * 128 + (rem & 7);
        float s = 0.0f;
#pragma unroll
        for (int d = 0; d < 16; ++d) s += p[d * 8];
        wsl[rr * 84 + rem] = s;
    }
    __syncthreads();
    int r = tid & 15, bgrp = tid >> 4;
    const float* urow = u + (size_t)(r0 + r) * 8;
    float4 ua[2][2];
#pragma unroll
    for (int j = 0; j < 2; ++j) {
        int b = b0 + j * 16 + bgrp;
        const float4* up = (const float4*)(urow + (size_t)b * K_);
        ua[j][0] = up[0]; ua[j][1] = up[1];
    }
#pragma unroll
    for (int c = 0; c < 10; ++c) {
        float4 w0 = *(const float4*)&wsl[r * 84 + c * 8];
        float4 w1 = *(const float4*)&wsl[r * 84 + c * 8 + 4];
#pragma unroll
        for (int j = 0; j < 2; ++j) {
            int b = b0 + j * 16 + bgrp;
            float s = ua[j][0].x * w0.x + ua[j][0].y * w0.y
                    + ua[j][0].z * w0.z + ua[j][0].w * w0.w
                    + ua[j][1].x * w1.x + ua[j][1].y * w1.y
                    + ua[j][1].z * w1.z + ua[j][1].w * w1.w;
            tT[((size_t)c * B_ + b) * R_ + r0 + r] = s;
        }
    }
}

// ---------------------------------------------------------------------------
// bupd body (R6-verified math): block unit (c, r0 tile of 64).
//   vs[b][d] = squash((sum_ks partials) * cw); cw = 1/1152 or 1/nsIn[n]
//   bij (+)= (1/B) sum_b vs*tT; E = exp(bij); nsOut[n] += sum_r E (atomics)
__device__ __forceinline__ void bupd_body(
    const float* __restrict__ partials, const float* __restrict__ tT,
    float* __restrict__ bij, float* __restrict__ E,
    float* __restrict__ nsOut, const float* __restrict__ nsIn,
    int accumulate, int c, int r0, int tid, float* smem) {
    float* vs  = smem;                    // [256][16]   4096
    float* red = smem + 4096;             // [16][258]   4128
    float* exs = smem + 8224;             // [4][16]       64
    {
        int d = tid & 15, bq = tid >> 4;
        const float* pp = partials + c * 16 + d;
        float inv = accumulate ? 1.0f / nsIn[c * 16 + d] : (1.0f / 1152.0f);
        for (int bb = 0; bb < 16; ++bb) {
            int b = bq * 16 + bb;
            float s = 0.0f;
#pragma unroll
            for (int ks = 0; ks < KS_; ++ks) s += pp[(size_t)ks * (B_ * N_) + b * N_];
            s *= inv;
            float sq = s * s;
            vs[b * 16 + d] = sq / (1.0f + sq) * s / (sqrtf(sq) + 1e-5f);
        }
    }
    __syncthreads();

    int rsub = tid & 63, bs = tid >> 6;
    float acc[16];
#pragma unroll
    for (int d = 0; d < 16; ++d) acc[d] = 0.0f;
    const float* tp = tT + (size_t)c * B_ * R_ + r0 + rsub;
    for (int bb = 0; bb < 64; ++bb) {
        int b = bb * 4 + bs;
        float tv = tp[(size_t)b * R_];
        const float4* vrow = (const float4*)(vs + b * 16);
        float4 v0 = vrow[0], v1 = vrow[1], v2 = vrow[2], v3 = vrow[3];
        acc[0]  = fmaf(tv, v0.x, acc[0]);  acc[1]  = fmaf(tv, v0.y, acc[1]);
        acc[2]  = fmaf(tv, v0.z, acc[2]);  acc[3]  = fmaf(tv, v0.w, acc[3]);
        acc[4]  = fmaf(tv, v1.x, acc[4]);  acc[5]  = fmaf(tv, v1.y, acc[5]);
        acc[6]  = fmaf(tv, v1.z, acc[6]);  acc[7]  = fmaf(tv, v1.w, acc[7]);
        acc[8]  = fmaf(tv, v2.x, acc[8]);  acc[9]  = fmaf(tv, v2.y, acc[9]);
        acc[10] = fmaf(tv, v2.z, acc[10]); acc[11] = fmaf(tv, v2.w, acc[11]);
        acc[12] = fmaf(tv, v3.x, acc[12]); acc[13] = fmaf(tv, v3.y, acc[13]);
        acc[14] = fmaf(tv, v3.z, acc[14]); acc[15] = fmaf(tv, v3.w, acc[15]);
    }
#pragma unroll
    for (int d = 0; d < 16; ++d) red[d * 258 + tid] = acc[d];
    __syncthreads();

    int d2 = tid & 15, rg = tid >> 4;
    float exacc = 0.0f;
#pragma unroll
    for (int j = 0; j < 4; ++j) {
        int rr = rg + j * 16;
        const float* rp = red + d2 * 258 + rr;
        float s = (rp[0] + rp[64] + rp[128] + rp[192]) * (1.0f / B_);
        int o = (r0 + rr) * N_ + c * 16 + d2;
        if (accumulate) s += bij[o];
        bij[o] = s;
        float ex = __expf(s);
        E[o] = ex;
        exacc += ex;
    }
    exacc += __shfl_down(exacc, 16, 64);
    exacc += __shfl_down(exacc, 32, 64);
    int wv = tid >> 6, ln = tid & 63;
    if (ln < 16) exs[wv * 16 + ln] = exacc;
    __syncthreads();
    if (tid < 16)
        atomicAdd(&nsOut[c * 16 + tid],
                  exs[tid] + exs[16 + tid] + exs[32 + tid] + exs[48 + tid]);
}

// ---------------------------------------------------------------------------
__launch_bounds__(256, 2)
__global__ void digicaps_persistent(const float* __restrict__ u,
                                    const float* __restrict__ W,
                                    float* __restrict__ out,
                                    float* __restrict__ ws) {
    __shared__ float smem[10240];   // 40 KB, reused by every stage
    float* tT       = ws + OFF_TT;
    float* bij      = ws + OFF_BIJ;
    float* E        = ws + OFF_E;
    float* nsumA    = ws + OFF_NSA;
    float* nsumB    = ws + OFF_NSB;
    float* partials = ws + OFF_PART;
    int*   bar      = (int*)(ws + OFF_BAR);

    int bid = blockIdx.x, tid = threadIdx.x;
    int bt = bid & 15, ks = bid >> 4;

    // ---- Stage A: gemm<0> + nsum zero + tT (576 units over all blocks)
    gemm_body<0>(u, W, nullptr, partials, smem, bt, ks, tid);
    if (bid == 0 && tid < N_) { nsumA[tid] = 0.0f; nsumB[tid] = 0.0f; }
    tT_unit(u, W, tT, bid, tid, smem);
    if (bid < 64) tT_unit(u, W, tT, 512 + bid, tid, smem);
    gridbar(bar, NB_ * 1);

    // ---- Stage B: bupd iter0 (blocks 0-179)
    if (bid < 180) bupd_body(partials, tT, bij, E, nsumA, nullptr, 0,
                             bid % 10, (bid / 10) * 64, tid, smem);
    gridbar(bar, NB_ * 2);

    // ---- Stage C: gemm<1>
    gemm_body<1>(u, W, E, partials, smem, bt, ks, tid);
    gridbar(bar, NB_ * 3);

    // ---- Stage D: bupd iter1 (accumulate)
    if (bid < 180) bupd_body(partials, tT, bij, E, nsumB, nsumA, 1,
                             bid % 10, (bid / 10) * 64, tid, smem);
    gridbar(bar, NB_ * 4);

    // ---- Stage E: gemm<1>
    gemm_body<1>(u, W, E, partials, smem, bt, ks, tid);
    gridbar(bar, NB_ * 5);

    // ---- Stage F: rsv_out (blocks 0-159)
    if (bid < 160) {
        int g = bid * 256 + tid;
        float s = 0.0f;
#pragma unroll
        for (int k = 0; k < KS_; ++k) s += partials[(size_t)k * (B_ * N_) + g];
        s /= nsumB[g % N_];
        float sq = s * s;
        out[g] = sq / (1.0f + sq) * s / (sqrtf(sq) + 1e-5f);
    }
}

// ---------------------------------------------------------------------------
extern "C" void kernel_launch(void* const* d_in, const int* in_sizes, int n_in,
                              void* d_out, int out_size, void* d_ws, size_t ws_size,
                              hipStream_t stream) {
    (void)in_sizes; (void)n_in; (void)out_size; (void)ws_size;
    const float* u = (const float*)d_in[0];
    const float* W = (const float*)d_in[1];
    float* out = (float*)d_out;
    float* ws = (float*)d_ws;

    // zero the barrier counter (workspace is poisoned before every run);
    // memset node is captured into the graph so every replay re-zeroes.
    hipMemsetAsync(ws + OFF_BAR, 0, 256, stream);
    hipLaunchKernelGGL(digicaps_persistent, dim3(NB_), dim3(256), 0, stream,
                       u, W, out, ws);
}

// Round 8
// 434.523 us; speedup vs baseline: 1.7962x; 1.7962x over previous
//
#include <hip/hip_runtime.h>
#include <math.h>

// R20: PERSISTENT KERNEL, BARRIER FIXED. R7 ran 736 us with VALUBusy=4%,
// HBM=277 GB/s: the gridbar spin polled with ACQUIRE at agent scope, and each
// acquire poll emits buffer_inv (L1+L2 invalidate) on gfx950 -> 512 spinners
// invalidated the L2 thousands of times per us for the whole kernel, running
// every stage at cold-miss latency. Fix: RELAXED poll (agent-scope relaxed
// atomics still bypass non-coherent L2 via sc1 -> no stale-spin deadlock, no
// per-poll invalidate); ONE acquire __threadfence after the spin exits
// (release-fence -> relaxed-add / relaxed-load -> acquire-fence pattern).
// All stage bodies identical to R7 (passed, absmax 1.2e-4).

// Problem constants
#define R_   1152
#define C_   10
#define D_   16
#define I_   8
#define B_   256
#define N_   160      // C_*D_
#define K_   9216     // R_*I_
#define KS_  32       // K-split across blocks
#define KC_  288      // K_/KS_ per block (9 chunks of 32 k = 4 r-rows)
#define NB_  512      // persistent grid (2 blocks/CU x 256 CU)

// workspace layout (float offsets); ~18.5 MB
#define OFF_TT    0                      // 2,949,120  tT[c][b][r]
#define OFF_BIJ   2949120                //   184,320  bij[r][n]
#define OFF_E     (OFF_BIJ + 184320)     //   184,320  E[r][n] = exp(bij)
#define OFF_NSA   (OFF_E + 184320)       //       160  nsumA
#define OFF_NSB   (OFF_NSA + 160)        //       160  nsumB
#define OFF_PART  (OFF_NSB + 160)        // 1,310,720  partials[ks][b][n]
#define OFF_BAR   (OFF_PART + 1310720)   //        64  barrier counter (memset 0)

__device__ __forceinline__ float f4c(const float4 v, int i) {
    return i == 0 ? v.x : i == 1 ? v.y : i == 2 ? v.z : v.w;
}

// ---------------------------------------------------------------------------
// Device-scope grid barrier (fence-fence synchronization):
//   release __threadfence -> RELAXED fetch_add -> RELAXED spin -> one acquire
//   __threadfence. Relaxed agent-scope atomic ops go to the coherence point
//   (sc1) so the spin observes remote increments without invalidating caches.
__device__ __forceinline__ void gridbar(int* bar, int goal) {
    __syncthreads();
    if (threadIdx.x == 0) {
        __threadfence();   // release: make this block's stores visible
        __hip_atomic_fetch_add(bar, 1, __ATOMIC_RELAXED, __HIP_MEMORY_SCOPE_AGENT);
        while (__hip_atomic_load(bar, __ATOMIC_RELAXED, __HIP_MEMORY_SCOPE_AGENT) < goal)
            __builtin_amdgcn_s_sleep(16);
        __threadfence();   // acquire: ONE cache-inv after the barrier opens
    }
    __syncthreads();
}

// ---------------------------------------------------------------------------
// GEMM body (R1-proven): partials[ks][b*160+n] = sum_k u[b][k]*W[r][n][i]*cw,
// cw = E[r][n] (HASE) else 1. bt in [0,16), ks in [0,32). 40KB smem.
template <int HASE>
__device__ __forceinline__ void gemm_body(
    const float* __restrict__ u, const float* __restrict__ W,
    const float* __restrict__ E, float* __restrict__ partials,
    float* smem, int bt, int ks, int tid) {
    int wave = tid >> 6, lane = tid & 63;
    int ng = lane & 15, bg = lane >> 4;
    int b0 = bt * 16;
    int n0 = ng * 10;

    float acc[4][10];
#pragma unroll
    for (int m = 0; m < 4; ++m)
#pragma unroll
        for (int j = 0; j < 10; ++j) acc[m][j] = 0.0f;

    const float* ubase = u + (size_t)(b0 + bg * 4) * K_ + ks * KC_ + wave * 8;

    float4 wr[5];
    float  ee[5];
    float4 uc[8];
    {
        int r = ks * 36 + wave;
#pragma unroll
        for (int it = 0; it < 5; ++it) {
            int idx = it * 64 + lane;
            wr[it] = *(const float4*)(W + (size_t)r * 1280 + idx * 4);
            if (HASE) ee[it] = E[r * N_ + (idx >> 1)];
        }
#pragma unroll
        for (int m = 0; m < 4; ++m)
#pragma unroll
            for (int g = 0; g < 2; ++g)
                uc[m * 2 + g] = *(const float4*)(ubase + (size_t)m * K_ + g * 4);
    }

    int ldsbase = wave * 1280;
    for (int c = 0; c < 9; ++c) {
#pragma unroll
        for (int it = 0; it < 5; ++it) {
            int idx = it * 64 + lane;
            int n = idx >> 1, ih = (idx & 1) * 4;
            float e = HASE ? ee[it] : 1.0f;
            float* q = &smem[ldsbase + ih * 160 + n];
            q[0]   = wr[it].x * e;
            q[160] = wr[it].y * e;
            q[320] = wr[it].z * e;
            q[480] = wr[it].w * e;
        }
        float4 un[8];
        if (c < 8) {
            int r = ks * 36 + (c + 1) * 4 + wave;
#pragma unroll
            for (int it = 0; it < 5; ++it) {
                int idx = it * 64 + lane;
                wr[it] = *(const float4*)(W + (size_t)r * 1280 + idx * 4);
                if (HASE) ee[it] = E[r * N_ + (idx >> 1)];
            }
#pragma unroll
            for (int m = 0; m < 4; ++m)
#pragma unroll
                for (int g = 0; g < 2; ++g)
                    un[m * 2 + g] = *(const float4*)(ubase + (size_t)m * K_ + (c + 1) * 32 + g * 4);
        }
#pragma unroll
        for (int g = 0; g < 2; ++g) {
#pragma unroll
            for (int t4 = 0; t4 < 4; ++t4) {
                const float* wrow = &smem[ldsbase + (g * 4 + t4) * 160 + n0];
                float w[10];
#pragma unroll
                for (int j = 0; j < 10; j += 2) {
                    float2 ww = *(const float2*)(wrow + j);
                    w[j] = ww.x; w[j + 1] = ww.y;
                }
#pragma unroll
                for (int m = 0; m < 4; ++m) {
                    float uav = f4c(uc[m * 2 + g], t4);
#pragma unroll
                    for (int j = 0; j < 10; ++j)
                        acc[m][j] = fmaf(uav, w[j], acc[m][j]);
                }
            }
        }
        if (c < 8) {
#pragma unroll
            for (int q2 = 0; q2 < 8; ++q2) uc[q2] = un[q2];
        }
    }

    __syncthreads();
#pragma unroll
    for (int m = 0; m < 4; ++m)
#pragma unroll
        for (int j = 0; j < 10; ++j)
            smem[wave * 2560 + (bg * 4 + m) * N_ + n0 + j] = acc[m][j];
    __syncthreads();
    float* outp = partials + (size_t)ks * (B_ * N_) + (size_t)b0 * N_;
    for (int f = tid; f < 2560; f += 256)
        outp[f] = smem[f] + smem[2560 + f] + smem[5120 + f] + smem[7680 + f];
}

// ---------------------------------------------------------------------------
// tT unit (r-tile 16 x b-tile 32), 576 units over 512 blocks (64 do two):
//   wsl[rr][c*8+i] = sum_d W[r0+rr][c][d][i]  (redundant x8 b-tiles, L2-hot)
//   tT[c][b][r0+r] = sum_i wsl[r][c*8+i] * u[b][r0+r][i]   (64B write segs)
__device__ __forceinline__ void tT_unit(const float* __restrict__ u,
                                        const float* __restrict__ W,
                                        float* __restrict__ tT,
                                        int unit, int tid, float* wsl) {
    int r0 = (unit >> 3) * 16;
    int b0 = (unit & 7) * 32;
    __syncthreads();                        // smem handoff
    for (int q = tid; q < 1280; q += 256) {
        int rr = q / 80, rem = q % 80;      // rem = c*8+i
        const float* p = W + (size_t)(r0 + rr) * 1280 + (rem >> 3) * 128 + (rem & 7);
        float s = 0.0f;
#pragma unroll
        for (int d = 0; d < 16; ++d) s += p[d * 8];
        wsl[rr * 84 + rem] = s;
    }
    __syncthreads();
    int r = tid & 15, bgrp = tid >> 4;
    const float* urow = u + (size_t)(r0 + r) * 8;
    float4 ua[2][2];
#pragma unroll
    for (int j = 0; j < 2; ++j) {
        int b = b0 + j * 16 + bgrp;
        const float4* up = (const float4*)(urow + (size_t)b * K_);
        ua[j][0] = up[0]; ua[j][1] = up[1];
    }
#pragma unroll
    for (int c = 0; c < 10; ++c) {
        float4 w0 = *(const float4*)&wsl[r * 84 + c * 8];
        float4 w1 = *(const float4*)&wsl[r * 84 + c * 8 + 4];
#pragma unroll
        for (int j = 0; j < 2; ++j) {
            int b = b0 + j * 16 + bgrp;
            float s = ua[j][0].x * w0.x + ua[j][0].y * w0.y
                    + ua[j][0].z * w0.z + ua[j][0].w * w0.w
                    + ua[j][1].x * w1.x + ua[j][1].y * w1.y
                    + ua[j][1].z * w1.z + ua[j][1].w * w1.w;
            tT[((size_t)c * B_ + b) * R_ + r0 + r] = s;
        }
    }
}

// ---------------------------------------------------------------------------
// bupd body (R6-verified math): block unit (c, r0 tile of 64).
//   vs[b][d] = squash((sum_ks partials) * cw); cw = 1/1152 or 1/nsIn[n]
//   bij (+)= (1/B) sum_b vs*tT; E = exp(bij); nsOut[n] += sum_r E (atomics)
__device__ __forceinline__ void bupd_body(
    const float* __restrict__ partials, const float* __restrict__ tT,
    float* __restrict__ bij, float* __restrict__ E,
    float* __restrict__ nsOut, const float* __restrict__ nsIn,
    int accumulate, int c, int r0, int tid, float* smem) {
    float* vs  = smem;                    // [256][16]   4096
    float* red = smem + 4096;             // [16][258]   4128
    float* exs = smem + 8224;             // [4][16]       64
    {
        int d = tid & 15, bq = tid >> 4;
        const float* pp = partials + c * 16 + d;
        float inv = accumulate ? 1.0f / nsIn[c * 16 + d] : (1.0f / 1152.0f);
        for (int bb = 0; bb < 16; ++bb) {
            int b = bq * 16 + bb;
            float s = 0.0f;
#pragma unroll
            for (int ks = 0; ks < KS_; ++ks) s += pp[(size_t)ks * (B_ * N_) + b * N_];
            s *= inv;
            float sq = s * s;
            vs[b * 16 + d] = sq / (1.0f + sq) * s / (sqrtf(sq) + 1e-5f);
        }
    }
    __syncthreads();

    int rsub = tid & 63, bs = tid >> 6;
    float acc[16];
#pragma unroll
    for (int d = 0; d < 16; ++d) acc[d] = 0.0f;
    const float* tp = tT + (size_t)c * B_ * R_ + r0 + rsub;
    for (int bb = 0; bb < 64; ++bb) {
        int b = bb * 4 + bs;
        float tv = tp[(size_t)b * R_];
        const float4* vrow = (const float4*)(vs + b * 16);
        float4 v0 = vrow[0], v1 = vrow[1], v2 = vrow[2], v3 = vrow[3];
        acc[0]  = fmaf(tv, v0.x, acc[0]);  acc[1]  = fmaf(tv, v0.y, acc[1]);
        acc[2]  = fmaf(tv, v0.z, acc[2]);  acc[3]  = fmaf(tv, v0.w, acc[3]);
        acc[4]  = fmaf(tv, v1.x, acc[4]);  acc[5]  = fmaf(tv, v1.y, acc[5]);
        acc[6]  = fmaf(tv, v1.z, acc[6]);  acc[7]  = fmaf(tv, v1.w, acc[7]);
        acc[8]  = fmaf(tv, v2.x, acc[8]);  acc[9]  = fmaf(tv, v2.y, acc[9]);
        acc[10] = fmaf(tv, v2.z, acc[10]); acc[11] = fmaf(tv, v2.w, acc[11]);
        acc[12] = fmaf(tv, v3.x, acc[12]); acc[13] = fmaf(tv, v3.y, acc[13]);
        acc[14] = fmaf(tv, v3.z, acc[14]); acc[15] = fmaf(tv, v3.w, acc[15]);
    }
#pragma unroll
    for (int d = 0; d < 16; ++d) red[d * 258 + tid] = acc[d];
    __syncthreads();

    int d2 = tid & 15, rg = tid >> 4;
    float exacc = 0.0f;
#pragma unroll
    for (int j = 0; j < 4; ++j) {
        int rr = rg + j * 16;
        const float* rp = red + d2 * 258 + rr;
        float s = (rp[0] + rp[64] + rp[128] + rp[192]) * (1.0f / B_);
        int o = (r0 + rr) * N_ + c * 16 + d2;
        if (accumulate) s += bij[o];
        bij[o] = s;
        float ex = __expf(s);
        E[o] = ex;
        exacc += ex;
    }
    exacc += __shfl_down(exacc, 16, 64);
    exacc += __shfl_down(exacc, 32, 64);
    int wv = tid >> 6, ln = tid & 63;
    if (ln < 16) exs[wv * 16 + ln] = exacc;
    __syncthreads();
    if (tid < 16)
        atomicAdd(&nsOut[c * 16 + tid],
                  exs[tid] + exs[16 + tid] + exs[32 + tid] + exs[48 + tid]);
}

// ---------------------------------------------------------------------------
__launch_bounds__(256, 2)
__global__ void digicaps_persistent(const float* __restrict__ u,
                                    const float* __restrict__ W,
                                    float* __restrict__ out,
                                    float* __restrict__ ws) {
    __shared__ float smem[10240];   // 40 KB, reused by every stage
    float* tT       = ws + OFF_TT;
    float* bij      = ws + OFF_BIJ;
    float* E        = ws + OFF_E;
    float* nsumA    = ws + OFF_NSA;
    float* nsumB    = ws + OFF_NSB;
    float* partials = ws + OFF_PART;
    int*   bar      = (int*)(ws + OFF_BAR);

    int bid = blockIdx.x, tid = threadIdx.x;
    int bt = bid & 15, ks = bid >> 4;

    // ---- Stage A: gemm<0> + nsum zero + tT (576 units over all blocks)
    gemm_body<0>(u, W, nullptr, partials, smem, bt, ks, tid);
    if (bid == 0 && tid < N_) { nsumA[tid] = 0.0f; nsumB[tid] = 0.0f; }
    tT_unit(u, W, tT, bid, tid, smem);
    if (bid < 64) tT_unit(u, W, tT, 512 + bid, tid, smem);
    gridbar(bar, NB_ * 1);

    // ---- Stage B: bupd iter0 (blocks 0-179)
    if (bid < 180) bupd_body(partials, tT, bij, E, nsumA, nullptr, 0,
                             bid % 10, (bid / 10) * 64, tid, smem);
    gridbar(bar, NB_ * 2);

    // ---- Stage C: gemm<1>
    gemm_body<1>(u, W, E, partials, smem, bt, ks, tid);
    gridbar(bar, NB_ * 3);

    // ---- Stage D: bupd iter1 (accumulate)
    if (bid < 180) bupd_body(partials, tT, bij, E, nsumB, nsumA, 1,
                             bid % 10, (bid / 10) * 64, tid, smem);
    gridbar(bar, NB_ * 4);

    // ---- Stage E: gemm<1>
    gemm_body<1>(u, W, E, partials, smem, bt, ks, tid);
    gridbar(bar, NB_ * 5);

    // ---- Stage F: rsv_out (blocks 0-159)
    if (bid < 160) {
        int g = bid * 256 + tid;
        float s = 0.0f;
#pragma unroll
        for (int k = 0; k < KS_; ++k) s += partials[(size_t)k * (B_ * N_) + g];
        s /= nsumB[g % N_];
        float sq = s * s;
        out[g] = sq / (1.0f + sq) * s / (sqrtf(sq) + 1e-5f);
    }
}

// ---------------------------------------------------------------------------
extern "C" void kernel_launch(void* const* d_in, const int* in_sizes, int n_in,
                              void* d_out, int out_size, void* d_ws, size_t ws_size,
                              hipStream_t stream) {
    (void)in_sizes; (void)n_in; (void)out_size; (void)ws_size;
    const float* u = (const float*)d_in[0];
    const float* W = (const float*)d_in[1];
    float* out = (float*)d_out;
    float* ws = (float*)d_ws;

    // zero the barrier counter (captured into the graph so every replay re-zeroes)
    hipMemsetAsync(ws + OFF_BAR, 0, 256, stream);
    hipLaunchKernelGGL(digicaps_persistent, dim3(NB_), dim3(256), 0, stream,
                       u, W, out, ws);
}

// Round 9
// 230.203 us; speedup vs baseline: 3.3903x; 1.8876x over previous
//
#include <hip/hip_runtime.h>
#include <math.h>

// R21: PERSISTENT, FENCELESS. R8 (380us, VALU 7.7%) still paid ~60us/barrier:
// __threadfence at agent scope on multi-XCD gfx950 emits buffer_wbl2/buffer_inv
// -> 512 blocks x 5 barriers x 2 L2-wide TCC ops, serialized, plus cold u/W
// every stage. Fix: ALL cross-stage data moves via coherence-point (sc1)
// accesses -- __hip_atomic_{load,store,fetch_add} RELAXED/AGENT -- so no
// release-writeback or acquire-invalidate is needed at all. partials deleted:
// GEMM epilogues atomically accumulate into vacc[3][B][N] (memory-side f32
// atomics); bupd preamble reads 16KB of vacc (not 512KB of partials). u/W keep
// plain cached loads and stay L2-hot across all stages (no invalidates).
// gridbar = vmcnt drain -> relaxed add -> relaxed poll. Zero fences.

// Problem constants
#define R_   1152
#define C_   10
#define D_   16
#define I_   8
#define B_   256
#define N_   160      // C_*D_
#define K_   9216     // R_*I_
#define KS_  32       // K-split across blocks
#define KC_  288      // K_/KS_ per block (9 chunks of 32 k = 4 r-rows)
#define NB_  512      // persistent grid (2 blocks/CU x 256 CU)

// workspace layout (float offsets)
#define OFF_TT    0                      // 2,949,120  tT[c][b][r]
#define OFF_BIJ   2949120                //   184,320  bij[r][n]
#define OFF_E     (OFF_BIJ + 184320)     //   184,320  E[r][n] = exp(bij)
#define OFF_NSA   (OFF_E + 184320)       //       160  nsumA
#define OFF_NSB   (OFF_NSA + 160)        //       160  nsumB
#define OFF_VA    (OFF_NSB + 160)        //    40,960  vaccA[b][n]  (memset 0)
#define OFF_VB    (OFF_VA + 40960)       //    40,960  vaccB        (memset 0)
#define OFF_VC    (OFF_VB + 40960)       //    40,960  vaccC        (memset 0)
#define OFF_BAR   (OFF_VC + 40960)       //        64  barrier counter (memset 0)

#define SCOPE __HIP_MEMORY_SCOPE_AGENT

__device__ __forceinline__ float aload(const float* p) {
    return __hip_atomic_load((float*)p, __ATOMIC_RELAXED, SCOPE);
}
__device__ __forceinline__ void astore(float* p, float v) {
    __hip_atomic_store(p, v, __ATOMIC_RELAXED, SCOPE);
}
__device__ __forceinline__ void aadd(float* p, float v) {
    __hip_atomic_fetch_add(p, v, __ATOMIC_RELAXED, SCOPE);
}

__device__ __forceinline__ float f4c(const float4 v, int i) {
    return i == 0 ? v.x : i == 1 ? v.y : i == 2 ? v.z : v.w;
}

// ---------------------------------------------------------------------------
// Fence-free grid barrier. All cross-stage traffic is sc1 (coherence point),
// so release = drain vmcnt (write-through acks), acquire = nothing (sc1 reads
// cannot hit stale XCD-L2 lines). Counter protocol proven in R8.
__device__ __forceinline__ void gridbar(int* bar, int goal) {
    asm volatile("s_waitcnt vmcnt(0)" ::: "memory");   // publish my sc1 stores
    __syncthreads();
    if (threadIdx.x == 0) {
        __hip_atomic_fetch_add(bar, 1, __ATOMIC_RELAXED, SCOPE);
        while (__hip_atomic_load(bar, __ATOMIC_RELAXED, SCOPE) < goal)
            __builtin_amdgcn_s_sleep(16);
    }
    __syncthreads();
}

// ---------------------------------------------------------------------------
// GEMM body (R1-proven loop): acc = sum_k u[b][k]*W[r][n][i]*cw, cw = E (sc1)
// when HASE. Epilogue: atomic-accumulate the block's 16x160 tile into vacc.
template <int HASE>
__device__ __forceinline__ void gemm_body(
    const float* __restrict__ u, const float* __restrict__ W,
    const float* __restrict__ E, float* __restrict__ vacc,
    float* smem, int bt, int ks, int tid) {
    int wave = tid >> 6, lane = tid & 63;
    int ng = lane & 15, bg = lane >> 4;
    int b0 = bt * 16;
    int n0 = ng * 10;

    float acc[4][10];
#pragma unroll
    for (int m = 0; m < 4; ++m)
#pragma unroll
        for (int j = 0; j < 10; ++j) acc[m][j] = 0.0f;

    const float* ubase = u + (size_t)(b0 + bg * 4) * K_ + ks * KC_ + wave * 8;

    float4 wr[5];
    float  ee[5];
    float4 uc[8];
    {
        int r = ks * 36 + wave;
#pragma unroll
        for (int it = 0; it < 5; ++it) {
            int idx = it * 64 + lane;
            wr[it] = *(const float4*)(W + (size_t)r * 1280 + idx * 4);
            if (HASE) ee[it] = aload(&E[r * N_ + (idx >> 1)]);
        }
#pragma unroll
        for (int m = 0; m < 4; ++m)
#pragma unroll
            for (int g = 0; g < 2; ++g)
                uc[m * 2 + g] = *(const float4*)(ubase + (size_t)m * K_ + g * 4);
    }

    int ldsbase = wave * 1280;
    for (int c = 0; c < 9; ++c) {
#pragma unroll
        for (int it = 0; it < 5; ++it) {
            int idx = it * 64 + lane;
            int n = idx >> 1, ih = (idx & 1) * 4;
            float e = HASE ? ee[it] : 1.0f;
            float* q = &smem[ldsbase + ih * 160 + n];
            q[0]   = wr[it].x * e;
            q[160] = wr[it].y * e;
            q[320] = wr[it].z * e;
            q[480] = wr[it].w * e;
        }
        float4 un[8];
        if (c < 8) {
            int r = ks * 36 + (c + 1) * 4 + wave;
#pragma unroll
            for (int it = 0; it < 5; ++it) {
                int idx = it * 64 + lane;
                wr[it] = *(const float4*)(W + (size_t)r * 1280 + idx * 4);
                if (HASE) ee[it] = aload(&E[r * N_ + (idx >> 1)]);
            }
#pragma unroll
            for (int m = 0; m < 4; ++m)
#pragma unroll
                for (int g = 0; g < 2; ++g)
                    un[m * 2 + g] = *(const float4*)(ubase + (size_t)m * K_ + (c + 1) * 32 + g * 4);
        }
#pragma unroll
        for (int g = 0; g < 2; ++g) {
#pragma unroll
            for (int t4 = 0; t4 < 4; ++t4) {
                const float* wrow = &smem[ldsbase + (g * 4 + t4) * 160 + n0];
                float w[10];
#pragma unroll
                for (int j = 0; j < 10; j += 2) {
                    float2 ww = *(const float2*)(wrow + j);
                    w[j] = ww.x; w[j + 1] = ww.y;
                }
#pragma unroll
                for (int m = 0; m < 4; ++m) {
                    float uav = f4c(uc[m * 2 + g], t4);
#pragma unroll
                    for (int j = 0; j < 10; ++j)
                        acc[m][j] = fmaf(uav, w[j], acc[m][j]);
                }
            }
        }
        if (c < 8) {
#pragma unroll
            for (int q2 = 0; q2 < 8; ++q2) uc[q2] = un[q2];
        }
    }

    __syncthreads();
#pragma unroll
    for (int m = 0; m < 4; ++m)
#pragma unroll
        for (int j = 0; j < 10; ++j)
            smem[wave * 2560 + (bg * 4 + m) * N_ + n0 + j] = acc[m][j];
    __syncthreads();
    float* outp = vacc + (size_t)b0 * N_;
    for (int f = tid; f < 2560; f += 256)
        aadd(&outp[f], smem[f] + smem[2560 + f] + smem[5120 + f] + smem[7680 + f]);
}

// ---------------------------------------------------------------------------
// tT unit (r-tile 16 x b-tile 32), 576 units over 512 blocks (64 do two):
//   wsl[rr][c*8+i] = sum_d W[r0+rr][c][d][i]   (plain cached W reads)
//   tT[c][b][r0+r] = sum_i wsl * u  -> sc1 store
__device__ __forceinline__ void tT_unit(const float* __restrict__ u,
                                        const float* __restrict__ W,
                                        float* __restrict__ tT,
                                        int unit, int tid, float* wsl) {
    int r0 = (unit >> 3) * 16;
    int b0 = (unit & 7) * 32;
    __syncthreads();                        // smem handoff
    for (int q = tid; q < 1280; q += 256) {
        int rr = q / 80, rem = q % 80;      // rem = c*8+i
        const float* p = W + (size_t)(r0 + rr) * 1280 + (rem >> 3) * 128 + (rem & 7);
        float s = 0.0f;
#pragma unroll
        for (int d = 0; d < 16; ++d) s += p[d * 8];
        wsl[rr * 84 + rem] = s;
    }
    __syncthreads();
    int r = tid & 15, bgrp = tid >> 4;
    const float* urow = u + (size_t)(r0 + r) * 8;
    float4 ua[2][2];
#pragma unroll
    for (int j = 0; j < 2; ++j) {
        int b = b0 + j * 16 + bgrp;
        const float4* up = (const float4*)(urow + (size_t)b * K_);
        ua[j][0] = up[0]; ua[j][1] = up[1];
    }
#pragma unroll
    for (int c = 0; c < 10; ++c) {
        float4 w0 = *(const float4*)&wsl[r * 84 + c * 8];
        float4 w1 = *(const float4*)&wsl[r * 84 + c * 8 + 4];
#pragma unroll
        for (int j = 0; j < 2; ++j) {
            int b = b0 + j * 16 + bgrp;
            float s = ua[j][0].x * w0.x + ua[j][0].y * w0.y
                    + ua[j][0].z * w0.z + ua[j][0].w * w0.w
                    + ua[j][1].x * w1.x + ua[j][1].y * w1.y
                    + ua[j][1].z * w1.z + ua[j][1].w * w1.w;
            astore(&tT[((size_t)c * B_ + b) * R_ + r0 + r], s);
        }
    }
}

// ---------------------------------------------------------------------------
// bupd body: unit (c, r0 tile of 64), 180 units.
//   vs[b][d] = squash(vacc[b][c16+d] * cw)  -- 16KB sc1 reads (was 512KB)
//   bij (+)= (1/B) sum_b vs*tT (sc1); E = exp(bij) (sc1); nsOut += sum_r E
__device__ __forceinline__ void bupd_body(
    const float* __restrict__ vacc, const float* __restrict__ tT,
    float* __restrict__ bij, float* __restrict__ E,
    float* __restrict__ nsOut, const float* __restrict__ nsIn,
    int accumulate, int c, int r0, int tid, float* smem) {
    float* vs  = smem;                    // [256][16]   4096
    float* red = smem + 4096;             // [16][258]   4128
    float* exs = smem + 8224;             // [4][16]       64
    {
        int d = tid & 15, bq = tid >> 4;
        float inv = accumulate ? 1.0f / aload(&nsIn[c * 16 + d]) : (1.0f / 1152.0f);
        for (int bb = 0; bb < 16; ++bb) {
            int b = bq * 16 + bb;
            float s = aload(&vacc[(size_t)b * N_ + c * 16 + d]) * inv;
            float sq = s * s;
            vs[b * 16 + d] = sq / (1.0f + sq) * s / (sqrtf(sq) + 1e-5f);
        }
    }
    __syncthreads();

    int rsub = tid & 63, bs = tid >> 6;
    float acc[16];
#pragma unroll
    for (int d = 0; d < 16; ++d) acc[d] = 0.0f;
    const float* tp = tT + (size_t)c * B_ * R_ + r0 + rsub;
    for (int bb = 0; bb < 64; ++bb) {
        int b = bb * 4 + bs;
        float tv = aload(&tp[(size_t)b * R_]);
        const float4* vrow = (const float4*)(vs + b * 16);
        float4 v0 = vrow[0], v1 = vrow[1], v2 = vrow[2], v3 = vrow[3];
        acc[0]  = fmaf(tv, v0.x, acc[0]);  acc[1]  = fmaf(tv, v0.y, acc[1]);
        acc[2]  = fmaf(tv, v0.z, acc[2]);  acc[3]  = fmaf(tv, v0.w, acc[3]);
        acc[4]  = fmaf(tv, v1.x, acc[4]);  acc[5]  = fmaf(tv, v1.y, acc[5]);
        acc[6]  = fmaf(tv, v1.z, acc[6]);  acc[7]  = fmaf(tv, v1.w, acc[7]);
        acc[8]  = fmaf(tv, v2.x, acc[8]);  acc[9]  = fmaf(tv, v2.y, acc[9]);
        acc[10] = fmaf(tv, v2.z, acc[10]); acc[11] = fmaf(tv, v2.w, acc[11]);
        acc[12] = fmaf(tv, v3.x, acc[12]); acc[13] = fmaf(tv, v3.y, acc[13]);
        acc[14] = fmaf(tv, v3.z, acc[14]); acc[15] = fmaf(tv, v3.w, acc[15]);
    }
#pragma unroll
    for (int d = 0; d < 16; ++d) red[d * 258 + tid] = acc[d];
    __syncthreads();

    int d2 = tid & 15, rg = tid >> 4;
    float exacc = 0.0f;
#pragma unroll
    for (int j = 0; j < 4; ++j) {
        int rr = rg + j * 16;
        const float* rp = red + d2 * 258 + rr;
        float s = (rp[0] + rp[64] + rp[128] + rp[192]) * (1.0f / B_);
        int o = (r0 + rr) * N_ + c * 16 + d2;
        if (accumulate) s += aload(&bij[o]);
        astore(&bij[o], s);
        float ex = __expf(s);
        astore(&E[o], ex);
        exacc += ex;
    }
    exacc += __shfl_down(exacc, 16, 64);
    exacc += __shfl_down(exacc, 32, 64);
    int wv = tid >> 6, ln = tid & 63;
    if (ln < 16) exs[wv * 16 + ln] = exacc;
    __syncthreads();
    if (tid < 16)
        aadd(&nsOut[c * 16 + tid],
             exs[tid] + exs[16 + tid] + exs[32 + tid] + exs[48 + tid]);
}

// ---------------------------------------------------------------------------
__launch_bounds__(256, 2)
__global__ void digicaps_persistent(const float* __restrict__ u,
                                    const float* __restrict__ W,
                                    float* __restrict__ out,
                                    float* __restrict__ ws) {
    __shared__ float smem[10240];   // 40 KB, reused by every stage
    float* tT    = ws + OFF_TT;
    float* bij   = ws + OFF_BIJ;
    float* E     = ws + OFF_E;
    float* nsumA = ws + OFF_NSA;
    float* nsumB = ws + OFF_NSB;
    float* vaccA = ws + OFF_VA;
    float* vaccB = ws + OFF_VB;
    float* vaccC = ws + OFF_VC;
    int*   bar   = (int*)(ws + OFF_BAR);

    int bid = blockIdx.x, tid = threadIdx.x;
    int bt = bid & 15, ks = bid >> 4;

    // ---- Stage A: gemm<0> -> vaccA, nsum zero, tT (576 units, concurrent)
    if (bid == 0 && tid < N_) { astore(&nsumA[tid], 0.0f); astore(&nsumB[tid], 0.0f); }
    gemm_body<0>(u, W, nullptr, vaccA, smem, bt, ks, tid);
    tT_unit(u, W, tT, bid, tid, smem);
    if (bid < 64) tT_unit(u, W, tT, 512 + bid, tid, smem);
    gridbar(bar, NB_ * 1);

    // ---- Stage B: bupd iter0 (blocks 0-179)
    if (bid < 180) bupd_body(vaccA, tT, bij, E, nsumA, nullptr, 0,
                             bid % 10, (bid / 10) * 64, tid, smem);
    gridbar(bar, NB_ * 2);

    // ---- Stage C: gemm<1> -> vaccB
    gemm_body<1>(u, W, E, vaccB, smem, bt, ks, tid);
    gridbar(bar, NB_ * 3);

    // ---- Stage D: bupd iter1 (accumulate, /nsumA)
    if (bid < 180) bupd_body(vaccB, tT, bij, E, nsumB, nsumA, 1,
                             bid % 10, (bid / 10) * 64, tid, smem);
    gridbar(bar, NB_ * 4);

    // ---- Stage E: gemm<1> -> vaccC
    gemm_body<1>(u, W, E, vaccC, smem, bt, ks, tid);
    gridbar(bar, NB_ * 5);

    // ---- Stage F: out = squash(vaccC / nsumB)  (blocks 0-159)
    if (bid < 160) {
        int g = bid * 256 + tid;
        float s = aload(&vaccC[g]) / aload(&nsumB[g % N_]);
        float sq = s * s;
        out[g] = sq / (1.0f + sq) * s / (sqrtf(sq) + 1e-5f);
    }
}

// ---------------------------------------------------------------------------
extern "C" void kernel_launch(void* const* d_in, const int* in_sizes, int n_in,
                              void* d_out, int out_size, void* d_ws, size_t ws_size,
                              hipStream_t stream) {
    (void)in_sizes; (void)n_in; (void)out_size; (void)ws_size;
    const float* u = (const float*)d_in[0];
    const float* W = (const float*)d_in[1];
    float* out = (float*)d_out;
    float* ws = (float*)d_ws;

    // zero vaccA/B/C + barrier counter (contiguous; captured into the graph)
    hipMemsetAsync(ws + OFF_VA, 0, (3 * 40960 + 64) * sizeof(float), stream);
    hipLaunchKernelGGL(digicaps_persistent, dim3(NB_), dim3(256), 0, stream,
                       u, W, out, ws);
}